// Round 19
// baseline (155.467 us; speedup 1.0000x reference)
//
#include <hip/hip_runtime.h>

typedef _Float16 f16;
typedef _Float16 f16x4 __attribute__((ext_vector_type(4)));
typedef _Float16 f16x8 __attribute__((ext_vector_type(8)));
typedef float    f32x4 __attribute__((ext_vector_type(4)));

#define BATCH 65536
#define INDIM 512
#define MD    64
#define MSZ   100
#define NCAT  35
#define CKSZ  5
#define ODIM  512
#define N1    256    // X cols: [bq(64) | cq(64) | S_raw(100) | pad(28)]
#define K2    128    // GEMM2 K: base attn 100 zero-padded to 128
#define NSLOT (NCAT*CKSZ)
#define RBS   232    // rb stride in f16 (cols 0..227 used)
#define CTS   280    // C2catT row stride in f16 (35 cats x 8-padded slots)

static __device__ __forceinline__ f32x4 mfma16(f16x4 a, f16x4 b, f32x4 c) {
  return __builtin_amdgcn_mfma_f32_16x16x16f16(a, b, c, 0, 0, 0);
}

#define GLD_LDS16(g, l)                                                        \
  __builtin_amdgcn_global_load_lds(                                            \
      (const __attribute__((address_space(1))) void*)(g),                      \
      (__attribute__((address_space(3))) void*)(l), 16, 0, 0)

// ===== prep: B1p frag-packed | B2p quad-packed | C2catT transposed | bias1 ==
// B1p quad idx: ((ntile*32 + kstep)*64 + lane)*4+j  = B1[ntile*16+(lane&15)][kstep*16+4*(lane>>4)+j]
// B2p quad idx: ((otile*8 + kstep)*64 + lane)*4+j  = B2[otile*16+(lane&15)][kstep*16+4*(lane>>4)+j]
// C2catT[col][8*ci+s] = s<5 ? cat_vals[ci*5+s]·W_out[col,64:128] : 0
// id ranges: [0,32768) B1p | [32768,49152) B2p | [49152,192512) C2catT | [192512,192768) bias1
__global__ __launch_bounds__(256) void k_prep(
    const float* __restrict__ Wb, const float* __restrict__ bb,
    const float* __restrict__ Wc, const float* __restrict__ bc,
    const float* __restrict__ keys, const float* __restrict__ bvals,
    const float* __restrict__ cvals, const float* __restrict__ Wo,
    f16* __restrict__ B1p, float* __restrict__ bias1,
    f16* __restrict__ B2p, f16* __restrict__ C2catT) {
  int id = blockIdx.x * 256 + threadIdx.x;
  if (id < 32768) {
    int l = id & 63, ntile = id >> 11;
    int n = ntile * 16 + (l & 15);
    int kb = ((id >> 6) & 31) * 16 + 4 * (l >> 4);
    float v0 = 0.f, v1 = 0.f, v2 = 0.f, v3 = 0.f;
    if (n < 64) {
      const float* w = Wb + n * INDIM + kb;
      v0 = w[0]; v1 = w[1]; v2 = w[2]; v3 = w[3];
    } else if (n < 128) {
      const float* w = Wc + (n - 64) * INDIM + kb;
      v0 = w[0]; v1 = w[1]; v2 = w[2]; v3 = w[3];
    } else if (n < 128 + MSZ) {
      int m = n - 128;
      float ss = 0.f;
      for (int d = 0; d < MD; d++) { float kv = keys[m * MD + d]; ss += kv * kv; }
      float rin = 1.f / fmaxf(sqrtf(ss), 1e-8f);
      for (int d = 0; d < MD; d++) {
        float kd = keys[m * MD + d];
        const float* wr = Wb + d * INDIM + kb;
        v0 += wr[0] * kd; v1 += wr[1] * kd; v2 += wr[2] * kd; v3 += wr[3] * kd;
      }
      v0 *= rin; v1 *= rin; v2 *= rin; v3 *= rin;
    }
    f16x4 o; o[0] = (f16)v0; o[1] = (f16)v1; o[2] = (f16)v2; o[3] = (f16)v3;
    *(f16x4*)(B1p + (size_t)id * 4) = o;
  } else if (id < 49152) {
    int q2 = id - 32768;
    int l = q2 & 63, otile = q2 >> 9;
    int o = otile * 16 + (l & 15);
    int kkb = ((q2 >> 6) & 7) * 16 + 4 * (l >> 4);
    float v0 = 0.f, v1 = 0.f, v2 = 0.f, v3 = 0.f;
    if (kkb < MSZ) {
      for (int d = 0; d < MD; d++) {
        float w = Wo[o * 128 + d];
        v0 += bvals[(kkb + 0) * MD + d] * w;
        v1 += bvals[(kkb + 1) * MD + d] * w;
        v2 += bvals[(kkb + 2) * MD + d] * w;
        v3 += bvals[(kkb + 3) * MD + d] * w;
      }
    }
    f16x4 o4; o4[0] = (f16)v0; o4[1] = (f16)v1; o4[2] = (f16)v2; o4[3] = (f16)v3;
    *(f16x4*)(B2p + (size_t)q2 * 4) = o4;
  } else if (id < 192512) {
    int id3 = id - 49152;               // 512*280 entries
    int col = id3 / CTS;
    int t = id3 - col * CTS;
    int ci = t >> 3, s = t & 7;
    float a = 0.f;
    if (s < CKSZ) {
      int slot = ci * CKSZ + s;
      for (int d = 0; d < MD; d++) a += cvals[slot * MD + d] * Wo[col * 128 + 64 + d];
    }
    C2catT[(size_t)col * CTS + t] = (f16)a;
  } else if (id < 192768) {
    int n = id - 192512;
    float bv = 0.f;
    if (n < 64) bv = bb[n];
    else if (n < 128) bv = bc[n - 64];
    else if (n < 128 + MSZ) {
      int m = n - 128;
      float ss = 0.f;
      for (int d = 0; d < MD; d++) { float kv = keys[m * MD + d]; ss += kv * kv; }
      float rin = 1.f / fmaxf(sqrtf(ss), 1e-8f);
      float a = 0.f;
      for (int d = 0; d < MD; d++) a += bb[d] * keys[m * MD + d];
      bv = a * rin;
    }
    bias1[n] = bv;
  }
}

// ===== fused GEMM1+mid: A manual-staged, B via global_load_lds (r18) =====
__global__ __launch_bounds__(512) void k_g1mid(const float* __restrict__ q,
    const f16* __restrict__ B1p, const float* __restrict__ bias1,
    const int* __restrict__ cidx, const float* __restrict__ catk,
    f16* __restrict__ A2, float* __restrict__ cwg, int* __restrict__ csg) {
  // union: staging (Al 18432B + Bl 32768B = 51200B) aliases rb (59392B)
  __shared__ __align__(16) char smem[128 * RBS * 2];
  f16 (*Al)[72] = (f16(*)[72])smem;              // [128][72]
  f16* BlF = (f16*)(smem + 18432);               // flat 32KB, fragment-linear
  char* BlB = smem + 18432;
  f16 (*rb)[RBS] = (f16(*)[RBS])smem;            // [128][232]

  const int tid = threadIdx.x;
  const int lane = tid & 63, wid = tid >> 6;
  const int wm = wid & 1, wn = wid >> 1;
  const int row0 = blockIdx.x * 128;
  const int l15 = lane & 15, l4 = lane >> 4;
  f32x4 acc[4][4];
#pragma unroll
  for (int i = 0; i < 4; i++)
#pragma unroll
    for (int j = 0; j < 4; j++) acc[i][j] = (f32x4){0.f, 0.f, 0.f, 0.f};

  const int arow = tid >> 2, aseg = tid & 3;   // A: 128 rows, 4x16 col segs
  const char* B1pB = (const char*)B1p;

  // ---- phase 1 K-loop: K-step 64; B async global->LDS (identity copy) ----
  for (int k0 = 0; k0 < INDIM; k0 += 64) {
    const float* qp = q + (size_t)(row0 + arow) * INDIM + k0 + aseg * 16;
    f32x4 a0 = *(const f32x4*)qp;
    f32x4 a1 = *(const f32x4*)(qp + 4);
    f32x4 a2 = *(const f32x4*)(qp + 8);
    f32x4 a3 = *(const f32x4*)(qp + 12);
    f16x8 av0, av1;
#pragma unroll
    for (int i = 0; i < 4; i++) { av0[i] = (f16)a0[i]; av0[4 + i] = (f16)a1[i]; }
#pragma unroll
    for (int i = 0; i < 4; i++) { av1[i] = (f16)a2[i]; av1[4 + i] = (f16)a3[i]; }
    __syncthreads();   // all waves done reading Al/Bl of prev iter
    {
      const int ksoff = (k0 >> 4) * 512;
#pragma unroll
      for (int c = 0; c < 4; c++) {
        const int t = wid * 2 + (c >> 1), h = (c & 1) * 1024;
        GLD_LDS16(B1pB + (size_t)t * 16384 + ksoff + h + lane * 16,
                  BlB + t * 2048 + h);
      }
    }
    *(f16x8*)&Al[arow][aseg * 16]     = av0;
    *(f16x8*)&Al[arow][aseg * 16 + 8] = av1;
    __syncthreads();   // drains vmcnt(0): Bl complete, Al visible
#pragma unroll
    for (int kk = 0; kk < 4; kk++) {
      const int kc = kk * 16 + 4 * l4;
      f16x4 af[4], bf[4];
#pragma unroll
      for (int mi = 0; mi < 4; mi++) af[mi] = *(const f16x4*)&Al[wm * 64 + mi * 16 + l15][kc];
#pragma unroll
      for (int ni = 0; ni < 4; ni++)
        bf[ni] = *(const f16x4*)(BlF + ((size_t)(wn * 4 + ni) * 4 + kk) * 256 + lane * 4);
#pragma unroll
      for (int mi = 0; mi < 4; mi++)
#pragma unroll
        for (int ni = 0; ni < 4; ni++)
          acc[mi][ni] = mfma16(af[mi], bf[ni], acc[mi][ni]);
    }
  }
  __syncthreads();   // all waves done reading Al/Bl before rb (alias) is written

  // ---- epilogue: acc -> rb (X rows in LDS; cols >= RBS unused) ----
#pragma unroll
  for (int ni = 0; ni < 4; ni++) {
    const int col = wn * 64 + ni * 16 + l15;
    const float bs = bias1[col];
    if (col < RBS) {
#pragma unroll
      for (int mi = 0; mi < 4; mi++) {
        const int r = wm * 64 + mi * 16 + 4 * l4;
#pragma unroll
        for (int j = 0; j < 4; j++)
          rb[r + j][col] = (f16)(acc[mi][ni][j] + bs);
      }
    }
  }
  __syncthreads();

  // ---- mid: 4 threads/row softmaxes (round-9/10/13-validated), in-place ----
  {
    const int row = tid >> 2, s = tid & 3;
    f16x8 v0 = *(const f16x8*)&rb[row][s * 16];
    f16x8 v1 = *(const f16x8*)&rb[row][s * 16 + 8];
    float nb = 0.f;
#pragma unroll
    for (int i = 0; i < 8; i++) { float x = (float)v0[i]; nb += x * x; }
#pragma unroll
    for (int i = 0; i < 8; i++) { float x = (float)v1[i]; nb += x * x; }
    nb += __shfl_xor(nb, 1, 64);
    nb += __shfl_xor(nb, 2, 64);
    const float rinv = 1.f / fmaxf(sqrtf(nb), 1e-8f);

    float sv[25];
#pragma unroll
    for (int i = 0; i < 25; i++)
      sv[i] = (float)rb[row][128 + s * 25 + i] * rinv;
    float mx = sv[0];
#pragma unroll
    for (int i = 1; i < 25; i++) mx = fmaxf(mx, sv[i]);
    mx = fmaxf(mx, __shfl_xor(mx, 1, 64));
    mx = fmaxf(mx, __shfl_xor(mx, 2, 64));
    float es = 0.f;
#pragma unroll
    for (int i = 0; i < 25; i++) { sv[i] = __expf(sv[i] - mx); es += sv[i]; }
    es += __shfl_xor(es, 1, 64);
    es += __shfl_xor(es, 2, 64);
    const float isum = 1.f / es;

    // category dots BEFORE overwriting (reads cols 64..127, disjoint anyway)
    const int ci = cidx[row0 + row];
    const float* kp = catk + (size_t)ci * (CKSZ * MD) + s * 16;
    f16x8 c0 = *(const f16x8*)&rb[row][64 + s * 16];
    f16x8 c1 = *(const f16x8*)&rb[row][64 + s * 16 + 8];
    float cqf[16];
#pragma unroll
    for (int i = 0; i < 8; i++) { cqf[i] = (float)c0[i]; cqf[8 + i] = (float)c1[i]; }
    float t[5];
#pragma unroll
    for (int sl = 0; sl < 5; sl++) {
      f32x4 k0 = *(const f32x4*)(kp + sl * MD);
      f32x4 k1 = *(const f32x4*)(kp + sl * MD + 4);
      f32x4 k2 = *(const f32x4*)(kp + sl * MD + 8);
      f32x4 k3 = *(const f32x4*)(kp + sl * MD + 12);
      float a = 0.f;
#pragma unroll
      for (int i = 0; i < 4; i++) a += cqf[i] * k0[i];
#pragma unroll
      for (int i = 0; i < 4; i++) a += cqf[4 + i] * k1[i];
#pragma unroll
      for (int i = 0; i < 4; i++) a += cqf[8 + i] * k2[i];
#pragma unroll
      for (int i = 0; i < 4; i++) a += cqf[12 + i] * k3[i];
      a += __shfl_xor(a, 1, 64);
      a += __shfl_xor(a, 2, 64);
      t[sl] = a;
    }

    // in-place: attn over own sims slice (no cross-thread readers afterwards)
#pragma unroll
    for (int i = 0; i < 25; i++)
      rb[row][128 + s * 25 + i] = (f16)(sv[i] * isum);

    if (s == 0) {
      float m5 = fmaxf(fmaxf(fmaxf(t[0], t[1]), fmaxf(t[2], t[3])), t[4]);
      float e0 = __expf(t[0] - m5), e1 = __expf(t[1] - m5), e2 = __expf(t[2] - m5),
            e3 = __expf(t[3] - m5), e4 = __expf(t[4] - m5);
      float ics = 1.f / (e0 + e1 + e2 + e3 + e4);
      float* cwr = cwg + (size_t)(row0 + row) * 5;
      cwr[0] = e0 * ics; cwr[1] = e1 * ics; cwr[2] = e2 * ics;
      cwr[3] = e3 * ics; cwr[4] = e4 * ics;
      csg[row0 + row] = ci * 8;   // 8-padded slot-group base for C2catT
    }
  }
  __syncthreads();

  // ---- stage out (round-13): A2[row][k] = k<100 ? rb[row][128+k] : 0 ----
  {
    const int row = tid >> 2, s = tid & 3;
    f16 tmp[32];
#pragma unroll
    for (int i = 0; i < 32; i++) {
      const int k = s * 32 + i;
      tmp[i] = (k < MSZ) ? rb[row][128 + k] : (f16)0.f;
    }
    f16* dst = A2 + (size_t)(row0 + row) * K2 + s * 32;
#pragma unroll
    for (int i = 0; i < 4; i++)
      *(f16x8*)(dst + i * 8) = *(const f16x8*)&tmp[i * 8];
  }
}

// ===== GEMM2: As LDS-staged, B2p frag-direct, vectorized cat gather =====
__global__ __launch_bounds__(512) void k_gemm2(const f16* __restrict__ A2,
    const f16* __restrict__ B2p, const float* __restrict__ cwg,
    const int* __restrict__ csg, const f16* __restrict__ C2catT,
    const float* __restrict__ bout, float* __restrict__ out) {
  __shared__ f16 As[128][136];
  __shared__ float cws[128][5];
  __shared__ int csi[128];
  const int tid = threadIdx.x;
  const int lane = tid & 63, wid = tid >> 6;
  const int wm = wid & 1, wn = wid >> 1;
  const int l15 = lane & 15, l4 = lane >> 4;
  const int row0 = blockIdx.x * 128;
  const int col0 = blockIdx.y * 256;

  {
    const int r = tid >> 2, seg = tid & 3;
    const f16* src = A2 + (size_t)(row0 + r) * K2 + seg * 32;
#pragma unroll
    for (int i = 0; i < 4; i++)
      *(f16x8*)&As[r][seg * 32 + i * 8] = *(const f16x8*)(src + i * 8);
  }
  if (tid < 128) {
#pragma unroll
    for (int i = 0; i < 5; i++) cws[tid][i] = cwg[(size_t)(row0 + tid) * 5 + i];
    csi[tid] = csg[row0 + tid];
  }
  __syncthreads();

  f32x4 acc[4][4];
#pragma unroll
  for (int i = 0; i < 4; i++)
#pragma unroll
    for (int j = 0; j < 4; j++) acc[i][j] = (f32x4){0.f, 0.f, 0.f, 0.f};

#pragma unroll
  for (int ks = 0; ks < 8; ks++) {
    f16x4 af[4], bf[4];
#pragma unroll
    for (int mi = 0; mi < 4; mi++)
      af[mi] = *(const f16x4*)&As[wm * 64 + mi * 16 + l15][ks * 16 + 4 * l4];
#pragma unroll
    for (int ni = 0; ni < 4; ni++)
      bf[ni] = *(const f16x4*)(B2p +
        (((size_t)(blockIdx.y * 16 + wn * 4 + ni) * 8 + ks) * 64 + lane) * 4);
#pragma unroll
    for (int mi = 0; mi < 4; mi++)
#pragma unroll
      for (int ni = 0; ni < 4; ni++)
        acc[mi][ni] = mfma16(af[mi], bf[ni], acc[mi][ni]);
  }

  float bs[4];
#pragma unroll
  for (int ni = 0; ni < 4; ni++) bs[ni] = bout[col0 + wn * 64 + ni * 16 + l15];
#pragma unroll
  for (int mi = 0; mi < 4; mi++) {
#pragma unroll
    for (int j = 0; j < 4; j++) {
      const int r = wm * 64 + mi * 16 + 4 * l4 + j;
      const int cb8 = csi[r];          // 8*ci
      const float w0 = cws[r][0], w1 = cws[r][1], w2 = cws[r][2],
                  w3 = cws[r][3], w4 = cws[r][4];
#pragma unroll
      for (int ni = 0; ni < 4; ni++) {
        const int col = col0 + wn * 64 + ni * 16 + l15;
        // one aligned 16B load delivers all 5 slot values for this (row,col)
        const f16x8 cv = *(const f16x8*)(C2catT + (size_t)col * CTS + cb8);
        float v = acc[mi][ni][j] + bs[ni];
        v += w0 * (float)cv[0]
           + w1 * (float)cv[1]
           + w2 * (float)cv[2]
           + w3 * (float)cv[3]
           + w4 * (float)cv[4];
        out[(size_t)(row0 + r) * ODIM + col] = v;
      }
    }
  }
}

extern "C" void kernel_launch(void* const* d_in, const int* in_sizes, int n_in,
                              void* d_out, int out_size, void* d_ws, size_t ws_size,
                              hipStream_t stream) {
  const float* query = (const float*)d_in[0];
  const int*   cidx  = (const int*)d_in[1];
  const float* Wb    = (const float*)d_in[2];
  const float* bb    = (const float*)d_in[3];
  const float* Wc    = (const float*)d_in[4];
  const float* bc    = (const float*)d_in[5];
  const float* bkeys = (const float*)d_in[6];
  const float* bvals = (const float*)d_in[7];
  const float* ckeys = (const float*)d_in[8];
  const float* cvals = (const float*)d_in[9];
  const float* Wo    = (const float*)d_in[10];
  const float* bo    = (const float*)d_in[11];
  float* out = (float*)d_out;

  char* ws = (char*)d_ws;
  f16*   A2     = (f16*)(ws);                          // 65536*128*2 = 16777216
  float* cwg    = (float*)(ws + 16777216);             // 65536*5*4   = 1310720
  int*   csg    = (int*)(ws + 18087936);               // 65536*4     = 262144
  f16*   B1p    = (f16*)(ws + 18350080);               // 32768*4*2   = 262144
  f16*   B2p    = (f16*)(ws + 18612224);               // 16384*4*2   = 131072
  f16*   C2catT = (f16*)(ws + 18743296);               // 512*280*2   = 286720
  float* bias1  = (float*)(ws + 19030016);             // 1024

  k_prep<<<dim3((192768 + 255) / 256), 256, 0, stream>>>(
      Wb, bb, Wc, bc, bkeys, bvals, cvals, Wo, B1p, bias1, B2p, C2catT);
  k_g1mid<<<dim3(BATCH / 128), 512, 0, stream>>>(
      query, B1p, bias1, cidx, ckeys, A2, cwg, csg);
  k_gemm2<<<dim3(BATCH / 128, 2), 512, 0, stream>>>(A2, B2p, cwg, csg, C2catT, bo, out);
}

// Round 20
// 101.196 us; speedup vs baseline: 1.5363x; 1.5363x over previous
//
#include <hip/hip_runtime.h>

typedef _Float16 f16;
typedef _Float16 f16x4 __attribute__((ext_vector_type(4)));
typedef _Float16 f16x8 __attribute__((ext_vector_type(8)));
typedef float    f32x4 __attribute__((ext_vector_type(4)));

#define BATCH 65536
#define INDIM 512
#define MD    64
#define MSZ   100
#define NCAT  35
#define CKSZ  5
#define ODIM  512
#define N1    256    // X cols: [bq(64) | cq(64) | S_raw(100) | pad(28)]
#define K2    192    // GEMM2 K: attn(100) | zero(28) | cvec(64)
#define RBS   232    // rb stride in f16 (cols 0..227 used)

static __device__ __forceinline__ f32x4 mfma16(f16x4 a, f16x4 b, f32x4 c) {
  return __builtin_amdgcn_mfma_f32_16x16x16f16(a, b, c, 0, 0, 0);
}

#define GLD_LDS16(g, l)                                                        \
  __builtin_amdgcn_global_load_lds(                                            \
      (const __attribute__((address_space(1))) void*)(g),                      \
      (__attribute__((address_space(3))) void*)(l), 16, 0, 0)

// ===== prep: B1p frag-packed | B2p quad-packed (K=192) | bias1 =====
// B1p quad idx: ((ntile*32 + kstep)*64 + lane)*4+j  = B1[ntile*16+(lane&15)][kstep*16+4*(lane>>4)+j]
// B2p quad idx: ((otile*12 + ks)*64 + lane)*4+j = B2[otile*16+(lane&15)][ks*16+4*(lane>>4)+j]
//   B2[o][kk] = kk<100 ? base_vals[kk]·W_out[o,:64] : kk<128 ? 0 : W_out[o][kk-64]
// id ranges: [0,32768) B1p | [32768,57344) B2p | [57344,57600) bias1
__global__ __launch_bounds__(256) void k_prep(
    const float* __restrict__ Wb, const float* __restrict__ bb,
    const float* __restrict__ Wc, const float* __restrict__ bc,
    const float* __restrict__ keys, const float* __restrict__ bvals,
    const float* __restrict__ Wo,
    f16* __restrict__ B1p, float* __restrict__ bias1, f16* __restrict__ B2p) {
  int id = blockIdx.x * 256 + threadIdx.x;
  if (id < 32768) {
    int l = id & 63, ntile = id >> 11;
    int n = ntile * 16 + (l & 15);
    int kb = ((id >> 6) & 31) * 16 + 4 * (l >> 4);
    float v0 = 0.f, v1 = 0.f, v2 = 0.f, v3 = 0.f;
    if (n < 64) {
      const float* w = Wb + n * INDIM + kb;
      v0 = w[0]; v1 = w[1]; v2 = w[2]; v3 = w[3];
    } else if (n < 128) {
      const float* w = Wc + (n - 64) * INDIM + kb;
      v0 = w[0]; v1 = w[1]; v2 = w[2]; v3 = w[3];
    } else if (n < 128 + MSZ) {
      int m = n - 128;
      float ss = 0.f;
      for (int d = 0; d < MD; d++) { float kv = keys[m * MD + d]; ss += kv * kv; }
      float rin = 1.f / fmaxf(sqrtf(ss), 1e-8f);
      for (int d = 0; d < MD; d++) {
        float kd = keys[m * MD + d];
        const float* wr = Wb + d * INDIM + kb;
        v0 += wr[0] * kd; v1 += wr[1] * kd; v2 += wr[2] * kd; v3 += wr[3] * kd;
      }
      v0 *= rin; v1 *= rin; v2 *= rin; v3 *= rin;
    }
    f16x4 o; o[0] = (f16)v0; o[1] = (f16)v1; o[2] = (f16)v2; o[3] = (f16)v3;
    *(f16x4*)(B1p + (size_t)id * 4) = o;
  } else if (id < 57344) {
    int q2 = id - 32768;
    int otile = q2 / 768;                 // 12 ks * 64 lanes
    int rem = q2 - otile * 768;
    int ks = rem >> 6, l = rem & 63;
    int o = otile * 16 + (l & 15);
    int kkb = ks * 16 + 4 * (l >> 4);
    float v0 = 0.f, v1 = 0.f, v2 = 0.f, v3 = 0.f;
    if (kkb < MSZ) {
      for (int d = 0; d < MD; d++) {
        float w = Wo[o * 128 + d];
        v0 += bvals[(kkb + 0) * MD + d] * w;
        v1 += bvals[(kkb + 1) * MD + d] * w;
        v2 += bvals[(kkb + 2) * MD + d] * w;
        v3 += bvals[(kkb + 3) * MD + d] * w;
      }
    } else if (kkb >= 128) {
      const float* w = Wo + o * 128 + (kkb - 64);   // kk-64 = 64 + (kk-128)
      v0 = w[0]; v1 = w[1]; v2 = w[2]; v3 = w[3];
    }
    f16x4 o4; o4[0] = (f16)v0; o4[1] = (f16)v1; o4[2] = (f16)v2; o4[3] = (f16)v3;
    *(f16x4*)(B2p + (size_t)q2 * 4) = o4;
  } else if (id < 57600) {
    int n = id - 57344;
    float bv = 0.f;
    if (n < 64) bv = bb[n];
    else if (n < 128) bv = bc[n - 64];
    else if (n < 128 + MSZ) {
      int m = n - 128;
      float ss = 0.f;
      for (int d = 0; d < MD; d++) { float kv = keys[m * MD + d]; ss += kv * kv; }
      float rin = 1.f / fmaxf(sqrtf(ss), 1e-8f);
      float a = 0.f;
      for (int d = 0; d < MD; d++) a += bb[d] * keys[m * MD + d];
      bv = a * rin;
    }
    bias1[n] = bv;
  }
}

// ===== fused GEMM1+mid: q -> A2[65536][192] (attn | 0 | cvec) =====
__global__ __launch_bounds__(512) void k_g1mid(const float* __restrict__ q,
    const f16* __restrict__ B1p, const float* __restrict__ bias1,
    const int* __restrict__ cidx, const float* __restrict__ catk,
    const float* __restrict__ cvals, f16* __restrict__ A2) {
  // union: staging (Al 18432B + Bl 32768B = 51200B) aliases rb (59392B)
  __shared__ __align__(16) char smem[128 * RBS * 2];
  f16 (*Al)[72] = (f16(*)[72])smem;              // [128][72]
  f16* BlF = (f16*)(smem + 18432);               // flat 32KB, fragment-linear
  char* BlB = smem + 18432;
  f16 (*rb)[RBS] = (f16(*)[RBS])smem;            // [128][232]

  const int tid = threadIdx.x;
  const int lane = tid & 63, wid = tid >> 6;
  const int wm = wid & 1, wn = wid >> 1;
  const int row0 = blockIdx.x * 128;
  const int l15 = lane & 15, l4 = lane >> 4;
  f32x4 acc[4][4];
#pragma unroll
  for (int i = 0; i < 4; i++)
#pragma unroll
    for (int j = 0; j < 4; j++) acc[i][j] = (f32x4){0.f, 0.f, 0.f, 0.f};

  const int arow = tid >> 2, aseg = tid & 3;   // A: 128 rows, 4x16 col segs
  const char* B1pB = (const char*)B1p;

  // ---- phase 1 K-loop: K-step 64; B async global->LDS (r18-validated) ----
  for (int k0 = 0; k0 < INDIM; k0 += 64) {
    const float* qp = q + (size_t)(row0 + arow) * INDIM + k0 + aseg * 16;
    f32x4 a0 = *(const f32x4*)qp;
    f32x4 a1 = *(const f32x4*)(qp + 4);
    f32x4 a2 = *(const f32x4*)(qp + 8);
    f32x4 a3 = *(const f32x4*)(qp + 12);
    f16x8 av0, av1;
#pragma unroll
    for (int i = 0; i < 4; i++) { av0[i] = (f16)a0[i]; av0[4 + i] = (f16)a1[i]; }
#pragma unroll
    for (int i = 0; i < 4; i++) { av1[i] = (f16)a2[i]; av1[4 + i] = (f16)a3[i]; }
    __syncthreads();   // all waves done reading Al/Bl of prev iter
    {
      const int ksoff = (k0 >> 4) * 512;
#pragma unroll
      for (int c = 0; c < 4; c++) {
        const int t = wid * 2 + (c >> 1), h = (c & 1) * 1024;
        GLD_LDS16(B1pB + (size_t)t * 16384 + ksoff + h + lane * 16,
                  BlB + t * 2048 + h);
      }
    }
    *(f16x8*)&Al[arow][aseg * 16]     = av0;
    *(f16x8*)&Al[arow][aseg * 16 + 8] = av1;
    __syncthreads();   // drains vmcnt(0): Bl complete, Al visible
#pragma unroll
    for (int kk = 0; kk < 4; kk++) {
      const int kc = kk * 16 + 4 * l4;
      f16x4 af[4], bf[4];
#pragma unroll
      for (int mi = 0; mi < 4; mi++) af[mi] = *(const f16x4*)&Al[wm * 64 + mi * 16 + l15][kc];
#pragma unroll
      for (int ni = 0; ni < 4; ni++)
        bf[ni] = *(const f16x4*)(BlF + ((size_t)(wn * 4 + ni) * 4 + kk) * 256 + lane * 4);
#pragma unroll
      for (int mi = 0; mi < 4; mi++)
#pragma unroll
        for (int ni = 0; ni < 4; ni++)
          acc[mi][ni] = mfma16(af[mi], bf[ni], acc[mi][ni]);
    }
  }
  __syncthreads();   // all waves done reading Al/Bl before rb (alias) is written

  // ---- epilogue: acc -> rb (X rows in LDS; cols >= RBS unused) ----
#pragma unroll
  for (int ni = 0; ni < 4; ni++) {
    const int col = wn * 64 + ni * 16 + l15;
    const float bs = bias1[col];
    if (col < RBS) {
#pragma unroll
      for (int mi = 0; mi < 4; mi++) {
        const int r = wm * 64 + mi * 16 + 4 * l4;
#pragma unroll
        for (int j = 0; j < 4; j++)
          rb[r + j][col] = (f16)(acc[mi][ni][j] + bs);
      }
    }
  }
  __syncthreads();

  // ---- mid: 4 threads/row softmaxes; attn in-place; cvec -> A2 direct ----
  {
    const int row = tid >> 2, s = tid & 3;
    f16x8 v0 = *(const f16x8*)&rb[row][s * 16];
    f16x8 v1 = *(const f16x8*)&rb[row][s * 16 + 8];
    float nb = 0.f;
#pragma unroll
    for (int i = 0; i < 8; i++) { float x = (float)v0[i]; nb += x * x; }
#pragma unroll
    for (int i = 0; i < 8; i++) { float x = (float)v1[i]; nb += x * x; }
    nb += __shfl_xor(nb, 1, 64);
    nb += __shfl_xor(nb, 2, 64);
    const float rinv = 1.f / fmaxf(sqrtf(nb), 1e-8f);

    float sv[25];
#pragma unroll
    for (int i = 0; i < 25; i++)
      sv[i] = (float)rb[row][128 + s * 25 + i] * rinv;
    float mx = sv[0];
#pragma unroll
    for (int i = 1; i < 25; i++) mx = fmaxf(mx, sv[i]);
    mx = fmaxf(mx, __shfl_xor(mx, 1, 64));
    mx = fmaxf(mx, __shfl_xor(mx, 2, 64));
    float es = 0.f;
#pragma unroll
    for (int i = 0; i < 25; i++) { sv[i] = __expf(sv[i] - mx); es += sv[i]; }
    es += __shfl_xor(es, 1, 64);
    es += __shfl_xor(es, 2, 64);
    const float isum = 1.f / es;

    // category dots (reads cols 64..127, disjoint from attn writes)
    const int ci = cidx[row0 + row];
    const float* kp = catk + (size_t)ci * (CKSZ * MD) + s * 16;
    f16x8 c0 = *(const f16x8*)&rb[row][64 + s * 16];
    f16x8 c1 = *(const f16x8*)&rb[row][64 + s * 16 + 8];
    float cqf[16];
#pragma unroll
    for (int i = 0; i < 8; i++) { cqf[i] = (float)c0[i]; cqf[8 + i] = (float)c1[i]; }
    float t[5];
#pragma unroll
    for (int sl = 0; sl < 5; sl++) {
      f32x4 k0 = *(const f32x4*)(kp + sl * MD);
      f32x4 k1 = *(const f32x4*)(kp + sl * MD + 4);
      f32x4 k2 = *(const f32x4*)(kp + sl * MD + 8);
      f32x4 k3 = *(const f32x4*)(kp + sl * MD + 12);
      float a = 0.f;
#pragma unroll
      for (int i = 0; i < 4; i++) a += cqf[i] * k0[i];
#pragma unroll
      for (int i = 0; i < 4; i++) a += cqf[4 + i] * k1[i];
#pragma unroll
      for (int i = 0; i < 4; i++) a += cqf[8 + i] * k2[i];
#pragma unroll
      for (int i = 0; i < 4; i++) a += cqf[12 + i] * k3[i];
      a += __shfl_xor(a, 1, 64);
      a += __shfl_xor(a, 2, 64);
      t[sl] = a;
    }

    // in-place: attn over own sims slice (cols 128..227)
#pragma unroll
    for (int i = 0; i < 25; i++)
      rb[row][128 + s * 25 + i] = (f16)(sv[i] * isum);

    // category weights (all 4 threads; redundant but removes cwg/csg)
    float m5 = fmaxf(fmaxf(fmaxf(t[0], t[1]), fmaxf(t[2], t[3])), t[4]);
    float e0 = __expf(t[0] - m5), e1 = __expf(t[1] - m5), e2 = __expf(t[2] - m5),
          e3 = __expf(t[3] - m5), e4 = __expf(t[4] - m5);
    const float ics = 1.f / (e0 + e1 + e2 + e3 + e4);
    float wv[5] = {e0 * ics, e1 * ics, e2 * ics, e3 * ics, e4 * ics};

    // cvec chunk d in [s*16, s*16+16): Sum_s wv[s] * cat_vals[ci*5+s][d]
    const float* vb = cvals + (size_t)(ci * CKSZ) * MD + s * 16;
    float cv[16];
#pragma unroll
    for (int i = 0; i < 16; i++) cv[i] = 0.f;
#pragma unroll
    for (int sl = 0; sl < 5; sl++) {
      f32x4 u0 = *(const f32x4*)(vb + sl * MD);
      f32x4 u1 = *(const f32x4*)(vb + sl * MD + 4);
      f32x4 u2 = *(const f32x4*)(vb + sl * MD + 8);
      f32x4 u3 = *(const f32x4*)(vb + sl * MD + 12);
      const float w = wv[sl];
#pragma unroll
      for (int i = 0; i < 4; i++) {
        cv[i]      += w * u0[i];
        cv[4 + i]  += w * u1[i];
        cv[8 + i]  += w * u2[i];
        cv[12 + i] += w * u3[i];
      }
    }
    f16x8 ch0, ch1;
#pragma unroll
    for (int i = 0; i < 8; i++) { ch0[i] = (f16)cv[i]; ch1[i] = (f16)cv[8 + i]; }
    f16* cdst = A2 + (size_t)(row0 + row) * K2 + 128 + s * 16;
    *(f16x8*)cdst = ch0;
    *(f16x8*)(cdst + 8) = ch1;
  }
  __syncthreads();

  // ---- stage out attn: A2[row][k] = k<100 ? rb[row][128+k] : 0 (k<128) ----
  {
    const int row = tid >> 2, s = tid & 3;
    f16 tmp[32];
#pragma unroll
    for (int i = 0; i < 32; i++) {
      const int k = s * 32 + i;
      tmp[i] = (k < MSZ) ? rb[row][128 + k] : (f16)0.f;
    }
    f16* dst = A2 + (size_t)(row0 + row) * K2 + s * 32;
#pragma unroll
    for (int i = 0; i < 4; i++)
      *(f16x8*)(dst + i * 8) = *(const f16x8*)&tmp[i * 8];
  }
}

// ===== GEMM2: dense K=192, pure bias epilogue (no gathers) =====
__global__ __launch_bounds__(512) void k_gemm2(const f16* __restrict__ A2,
    const f16* __restrict__ B2p, const float* __restrict__ bout,
    float* __restrict__ out) {
  __shared__ f16 As[128][200];
  const int tid = threadIdx.x;
  const int lane = tid & 63, wid = tid >> 6;
  const int wm = wid & 1, wn = wid >> 1;
  const int l15 = lane & 15, l4 = lane >> 4;
  const int row0 = blockIdx.x * 128;
  const int col0 = blockIdx.y * 256;

  {
    const int r = tid >> 2, seg = tid & 3;
    const f16* src = A2 + (size_t)(row0 + r) * K2 + seg * 48;
#pragma unroll
    for (int i = 0; i < 6; i++)
      *(f16x8*)&As[r][seg * 48 + i * 8] = *(const f16x8*)(src + i * 8);
  }
  __syncthreads();

  f32x4 acc[4][4];
#pragma unroll
  for (int i = 0; i < 4; i++)
#pragma unroll
    for (int j = 0; j < 4; j++) acc[i][j] = (f32x4){0.f, 0.f, 0.f, 0.f};

#pragma unroll
  for (int ks = 0; ks < 12; ks++) {
    f16x4 af[4], bf[4];
#pragma unroll
    for (int mi = 0; mi < 4; mi++)
      af[mi] = *(const f16x4*)&As[wm * 64 + mi * 16 + l15][ks * 16 + 4 * l4];
#pragma unroll
    for (int ni = 0; ni < 4; ni++)
      bf[ni] = *(const f16x4*)(B2p +
        (((size_t)(blockIdx.y * 16 + wn * 4 + ni) * 12 + ks) * 64 + lane) * 4);
#pragma unroll
    for (int mi = 0; mi < 4; mi++)
#pragma unroll
      for (int ni = 0; ni < 4; ni++)
        acc[mi][ni] = mfma16(af[mi], bf[ni], acc[mi][ni]);
  }

  float bs[4];
#pragma unroll
  for (int ni = 0; ni < 4; ni++) bs[ni] = bout[col0 + wn * 64 + ni * 16 + l15];
#pragma unroll
  for (int mi = 0; mi < 4; mi++) {
#pragma unroll
    for (int j = 0; j < 4; j++) {
      const int r = wm * 64 + mi * 16 + 4 * l4 + j;
#pragma unroll
      for (int ni = 0; ni < 4; ni++) {
        const int col = col0 + wn * 64 + ni * 16 + l15;
        out[(size_t)(row0 + r) * ODIM + col] = acc[mi][ni][j] + bs[ni];
      }
    }
  }
}

extern "C" void kernel_launch(void* const* d_in, const int* in_sizes, int n_in,
                              void* d_out, int out_size, void* d_ws, size_t ws_size,
                              hipStream_t stream) {
  const float* query = (const float*)d_in[0];
  const int*   cidx  = (const int*)d_in[1];
  const float* Wb    = (const float*)d_in[2];
  const float* bb    = (const float*)d_in[3];
  const float* Wc    = (const float*)d_in[4];
  const float* bc    = (const float*)d_in[5];
  const float* bkeys = (const float*)d_in[6];
  const float* bvals = (const float*)d_in[7];
  const float* ckeys = (const float*)d_in[8];
  const float* cvals = (const float*)d_in[9];
  const float* Wo    = (const float*)d_in[10];
  const float* bo    = (const float*)d_in[11];
  float* out = (float*)d_out;

  char* ws = (char*)d_ws;
  f16*   A2    = (f16*)(ws);                          // 65536*192*2 = 25165824
  f16*   B1p   = (f16*)(ws + 25165824);               // 32768*4*2   = 262144
  f16*   B2p   = (f16*)(ws + 25427968);               // 24576*4*2   = 196608
  float* bias1 = (float*)(ws + 25624576);             // 1024

  k_prep<<<dim3(57600 / 256), 256, 0, stream>>>(
      Wb, bb, Wc, bc, bkeys, bvals, Wo, B1p, bias1, B2p);
  k_g1mid<<<dim3(BATCH / 128), 512, 0, stream>>>(
      query, B1p, bias1, cidx, ckeys, cvals, A2);
  k_gemm2<<<dim3(BATCH / 128, 2), 512, 0, stream>>>(A2, B2p, bo, out);
}